// Round 6
// baseline (289.424 us; speedup 1.0000x reference)
//
#include <hip/hip_runtime.h>
#include <math.h>

// Problem constants
#define BB 2
#define TT 2048
#define DM 1024
#define NH 16
#define HD 64
#define FEAT 16
#define WIN 64
#define RTOT (BB*TT)        // 4096 rows

typedef __bf16 bf16x8 __attribute__((ext_vector_type(8)));
typedef float  f32x4  __attribute__((ext_vector_type(4)));

__device__ __forceinline__ unsigned short f2bf(float f) {
    union { float f; unsigned u; } v; v.f = f;
    unsigned r = v.u + 0x7FFFu + ((v.u >> 16) & 1u);   // RNE
    return (unsigned short)(r >> 16);
}
__device__ __forceinline__ float bf2f(unsigned short u) {
    union { unsigned u; float f; } v; v.u = ((unsigned)u) << 16; return v.f;
}

__device__ __forceinline__ void gl2lds16(const void* g, void* l) {
    __builtin_amdgcn_global_load_lds(
        (const __attribute__((address_space(1))) void*)g,
        (__attribute__((address_space(3))) void*)l, 16, 0, 0);
}

// ---------------------------------------------------------------------------
// Kernel 1: RMSNorm -> bf16 output
// ---------------------------------------------------------------------------
__global__ __launch_bounds__(256) void rmsnorm_kernel(const float* __restrict__ x,
                                                      const float* __restrict__ w,
                                                      unsigned short* __restrict__ h_bf) {
    int row = blockIdx.x;
    int tid = threadIdx.x;
    const float4* xr = (const float4*)(x + (size_t)row * DM);
    float4 xv = xr[tid];
    float ss = xv.x*xv.x + xv.y*xv.y + xv.z*xv.z + xv.w*xv.w;
    #pragma unroll
    for (int off = 32; off > 0; off >>= 1) ss += __shfl_down(ss, off, 64);
    __shared__ float red[4];
    if ((tid & 63) == 0) red[tid >> 6] = ss;
    __syncthreads();
    float tot = red[0] + red[1] + red[2] + red[3];
    float scale = rsqrtf(tot * (1.0f / DM) + 1e-6f);
    float4 wv = ((const float4*)w)[tid];
    ushort4 o;
    o.x = f2bf(xv.x * scale * wv.x);
    o.y = f2bf(xv.y * scale * wv.y);
    o.z = f2bf(xv.z * scale * wv.z);
    o.w = f2bf(xv.w * scale * wv.w);
    *(ushort4*)&h_bf[(size_t)row * DM + tid * 4] = o;
}

// ---------------------------------------------------------------------------
// Kernel 2: transpose + fp32->bf16.  W [K][N] fp32 -> WT [N][K] bf16.
// z = 0..2: QKV (K=1024); z = 3: Wout (K=2048). grid (16, 32, 4); QKV blocks
// with y>=16 exit early.
// ---------------------------------------------------------------------------
__global__ __launch_bounds__(256) void transpose_bf16_kernel(const float* __restrict__ W0,
                                                             const float* __restrict__ W1,
                                                             const float* __restrict__ W2,
                                                             const float* __restrict__ W3,
                                                             unsigned short* __restrict__ T0,
                                                             unsigned short* __restrict__ T1,
                                                             unsigned short* __restrict__ T2,
                                                             unsigned short* __restrict__ T3) {
    int z = blockIdx.z;
    int K = (z == 3) ? 2048 : 1024;
    const int N = 1024;
    if (blockIdx.y * 64 >= K) return;
    const float* W = (z == 0) ? W0 : (z == 1) ? W1 : (z == 2) ? W2 : W3;
    unsigned short* WT = (z == 0) ? T0 : (z == 1) ? T1 : (z == 2) ? T2 : T3;
    __shared__ float tile[64][65];
    int k0 = blockIdx.y * 64, n0 = blockIdx.x * 64;
    int t = threadIdx.x;
    int r = t >> 4, c4 = (t & 15) * 4;
    #pragma unroll
    for (int i = 0; i < 4; i++) {
        float4 vv = *(const float4*)&W[(size_t)(k0 + r + i*16) * N + n0 + c4];
        tile[r + i*16][c4 + 0] = vv.x;
        tile[r + i*16][c4 + 1] = vv.y;
        tile[r + i*16][c4 + 2] = vv.z;
        tile[r + i*16][c4 + 3] = vv.w;
    }
    __syncthreads();
    int rn = t >> 2, kq = (t & 3) * 16;
    unsigned short u[16];
    #pragma unroll
    for (int i = 0; i < 16; i++) u[i] = f2bf(tile[kq + i][rn]);
    size_t base = (size_t)(n0 + rn) * K + k0 + kq;
    *(uint4*)&WT[base]     = *(uint4*)&u[0];
    *(uint4*)&WT[base + 8] = *(uint4*)&u[8];
}

// ---------------------------------------------------------------------------
// bf16 MFMA GEMM core, double-buffered, strength-reduced staging:
// all global/LDS staging pointers and fragment LDS offsets precomputed;
// K-loop advances pointers by +32 elements (64 B) only. 128x128 tile, BK=32,
// XOR k-chunk permutation (ds_read_b128 conflicts <=2-way). Klen fixed 1024.
// ---------------------------------------------------------------------------
template<int LDA, int LDB>
__device__ __forceinline__ void gemm_core_db(const unsigned short* __restrict__ A,
                                             const unsigned short* __restrict__ BT,
                                             unsigned short* __restrict__ Cb,
                                             int k0g) {
    const int N = 1024;
    const int KITERS = 32;                   // 1024 / 32
    __shared__ __align__(16) unsigned short As[2 * 128 * 32];
    __shared__ __align__(16) unsigned short Bs[2 * 128 * 32];
    int tid = threadIdx.x;
    int lane = tid & 63;
    int w = tid >> 6;
    int wm = (w >> 1) * 64, wn = (w & 1) * 64;
    int m0 = blockIdx.y * 128, n0 = blockIdx.x * 128;
    int hi = lane >> 4;
    int l15 = lane & 15;

    // ---- staging constants (per thread): two slots c0=tid, c1=tid+256
    int c0 = tid, c1 = tid + 256;
    int r0 = c0 >> 2, kh0 = ((c0 & 3) - (r0 >> 1)) & 3;
    int r1 = c1 >> 2, kh1 = ((c1 & 3) - (r1 >> 1)) & 3;
    const unsigned short* aP0 = A  + (size_t)(m0 + r0) * LDA + k0g + kh0 * 8;
    const unsigned short* aP1 = A  + (size_t)(m0 + r1) * LDA + k0g + kh1 * 8;
    const unsigned short* bP0 = BT + (size_t)(n0 + r0) * LDB + k0g + kh0 * 8;
    const unsigned short* bP1 = BT + (size_t)(n0 + r1) * LDB + k0g + kh1 * 8;
    unsigned short* asD0 = &As[c0 * 8];
    unsigned short* asD1 = &As[c1 * 8];
    unsigned short* bsD0 = &Bs[c0 * 8];
    unsigned short* bsD1 = &Bs[c1 * 8];

    // ---- fragment LDS offsets (elements), fixed across iterations
    int aOff[4], bOff[4];
    #pragma unroll
    for (int i = 0; i < 4; i++) {
        int m = wm + i * 16 + l15;
        aOff[i] = m * 32 + (((hi + (m >> 1)) & 3) * 8);
        int n = wn + i * 16 + l15;
        bOff[i] = n * 32 + (((hi + (n >> 1)) & 3) * 8);
    }

    f32x4 acc[4][4];
    #pragma unroll
    for (int i = 0; i < 4; i++)
        #pragma unroll
        for (int j = 0; j < 4; j++)
            acc[i][j] = (f32x4){0.f, 0.f, 0.f, 0.f};

    // stage tile 0 into buffer 0
    gl2lds16(aP0, asD0); gl2lds16(aP1, asD1);
    gl2lds16(bP0, bsD0); gl2lds16(bP1, bsD1);

    for (int it = 0; it < KITERS; it++) {
        int cur = (it & 1) * 4096;
        int nxt = 4096 - cur;
        __syncthreads();                    // drains prefetch into cur
        if (it + 1 < KITERS) {
            aP0 += 32; aP1 += 32; bP0 += 32; bP1 += 32;
            gl2lds16(aP0, asD0 + nxt); gl2lds16(aP1, asD1 + nxt);
            gl2lds16(bP0, bsD0 + nxt); gl2lds16(bP1, bsD1 + nxt);
        }
        bf16x8 af[4], bfr[4];
        #pragma unroll
        for (int i = 0; i < 4; i++) {
            af[i]  = *(const bf16x8*)&As[cur + aOff[i]];
            bfr[i] = *(const bf16x8*)&Bs[cur + bOff[i]];
        }
        #pragma unroll
        for (int i = 0; i < 4; i++)
            #pragma unroll
            for (int j = 0; j < 4; j++)
                acc[i][j] = __builtin_amdgcn_mfma_f32_16x16x32_bf16(af[i], bfr[j], acc[i][j], 0, 0, 0);
    }
    #pragma unroll
    for (int i = 0; i < 4; i++) {
        #pragma unroll
        for (int j = 0; j < 4; j++) {
            int col = n0 + wn + j * 16 + l15;
            #pragma unroll
            for (int r = 0; r < 4; r++) {
                int row = m0 + wm + i * 16 + hi * 4 + r;
                Cb[(size_t)row * N + col] = f2bf(acc[i][j][r]);
            }
        }
    }
}

__global__ __launch_bounds__(256) void gemm_qkv_mfma(const unsigned short* __restrict__ A,
                                                     const unsigned short* __restrict__ BT0,
                                                     const unsigned short* __restrict__ BT1,
                                                     const unsigned short* __restrict__ BT2,
                                                     unsigned short* __restrict__ C0,
                                                     unsigned short* __restrict__ C1,
                                                     unsigned short* __restrict__ C2) {
    const unsigned short* BT = (blockIdx.z == 0) ? BT0 : (blockIdx.z == 1) ? BT1 : BT2;
    unsigned short* C = (blockIdx.z == 0) ? C0 : (blockIdx.z == 1) ? C1 : C2;
    gemm_core_db<1024, 1024>(A, BT, C, 0);
}

// Output GEMM, split-K=2: z-half computes bf16 partial P[z] over K-range z*1024.
__global__ __launch_bounds__(256) void gemm_out_mfma(const unsigned short* __restrict__ A,
                                                     const unsigned short* __restrict__ BT,
                                                     unsigned short* __restrict__ P0,
                                                     unsigned short* __restrict__ P1) {
    unsigned short* P = (blockIdx.z == 0) ? P0 : P1;
    gemm_core_db<2048, 2048>(A, BT, P, blockIdx.z * 1024);
}

// Reduce: out = x + P0 + P1   (float4-vectorized)
__global__ __launch_bounds__(256) void out_reduce_kernel(const float* __restrict__ x,
                                                         const unsigned short* __restrict__ P0,
                                                         const unsigned short* __restrict__ P1,
                                                         float* __restrict__ out) {
    int g = blockIdx.x * 256 + threadIdx.x;
    size_t e = (size_t)g * 4;
    float4 xv = *(const float4*)&x[e];
    ushort4 a = *(const ushort4*)&P0[e];
    ushort4 b = *(const ushort4*)&P1[e];
    float4 o;
    o.x = xv.x + bf2f(a.x) + bf2f(b.x);
    o.y = xv.y + bf2f(a.y) + bf2f(b.y);
    o.z = xv.z + bf2f(a.z) + bf2f(b.z);
    o.w = xv.w + bf2f(a.w) + bf2f(b.w);
    *(float4*)&out[e] = o;
}

// ---------------------------------------------------------------------------
// Kernel 3: feature projection (bf16 in, bf16 out)
// ---------------------------------------------------------------------------
__global__ __launch_bounds__(256) void feat_kernel(const unsigned short* __restrict__ qb,
                                                   const unsigned short* __restrict__ kb,
                                                   const float* __restrict__ Wqf,
                                                   const float* __restrict__ Wkf,
                                                   unsigned short* __restrict__ qf,
                                                   unsigned short* __restrict__ kf) {
    __shared__ float Wl[HD * FEAT];
    const unsigned short* src = blockIdx.z ? kb : qb;
    const float* Wm = blockIdx.z ? Wkf : Wqf;
    unsigned short* dst = blockIdx.z ? kf : qf;
    int tid = threadIdx.x;
    ((float4*)Wl)[tid] = ((const float4*)Wm)[tid];
    __syncthreads();
    int gid = blockIdx.x * 256 + tid;
    int f = gid & 15;
    int rowh = gid >> 4;
    const unsigned short* s = src + (size_t)rowh * HD;
    float acc = 0.f;
    #pragma unroll
    for (int d = 0; d < HD; d++) acc += bf2f(s[d]) * Wl[d * FEAT + f];
    dst[gid] = f2bf(acc);
}

// ---------------------------------------------------------------------------
// Kernel 4: sliding-window attention, single-shot MFMA flash tile.
// ---------------------------------------------------------------------------
__global__ __launch_bounds__(256) void win_mfma_kernel(const unsigned short* __restrict__ q_bf,
                                                       const unsigned short* __restrict__ k_bf,
                                                       const unsigned short* __restrict__ v_bf,
                                                       unsigned short* __restrict__ cat_bf) {
    int qtile = blockIdx.x;
    int bh = blockIdx.y;
    int h = bh & 15;
    int b = bh >> 4;
    int tid = threadIdx.x;
    int lane = tid & 63;
    int wv = tid >> 6;
    int qr0 = wv * 16;
    int t0 = qtile * 64;
    int k0 = t0 - 64;

    __shared__ __align__(16) unsigned short Qs[64 * 64];
    __shared__ __align__(16) unsigned short Ks[128 * 64];
    __shared__ __align__(16) unsigned short Vt[64 * 128];
    __shared__ __align__(16) unsigned short Pl[64 * 128];

    #pragma unroll
    for (int half = 0; half < 2; half++) {
        int slot = tid + half * 256;
        int row = slot >> 3, pos = slot & 7;
        int o = (pos - row) & 7;
        gl2lds16(q_bf + (size_t)(b * TT + t0 + row) * (NH * HD) + h * HD + o * 8,
                 &Qs[slot * 8]);
    }
    #pragma unroll
    for (int qd = 0; qd < 4; qd++) {
        int slot = tid + qd * 256;
        int row = slot >> 3, pos = slot & 7;
        int o = (pos - row) & 7;
        int kg = k0 + row;
        if (kg >= 0) {
            gl2lds16(k_bf + (size_t)(b * TT + kg) * (NH * HD) + h * HD + o * 8,
                     &Ks[slot * 8]);
        } else {
            uint4 z = {0, 0, 0, 0};
            *(uint4*)&Ks[slot * 8] = z;
        }
    }
    {
        int kk = tid & 127;
        int dh = tid >> 7;
        int kg = k0 + kk;
        unsigned short tmp[32];
        if (kg >= 0) {
            size_t base = (size_t)(b * TT + kg) * (NH * HD) + h * HD + dh * 32;
            *(uint4*)&tmp[0]  = *(const uint4*)&v_bf[base];
            *(uint4*)&tmp[8]  = *(const uint4*)&v_bf[base + 8];
            *(uint4*)&tmp[16] = *(const uint4*)&v_bf[base + 16];
            *(uint4*)&tmp[24] = *(const uint4*)&v_bf[base + 24];
        } else {
            #pragma unroll
            for (int d = 0; d < 32; d++) tmp[d] = 0;
        }
        int o = kk >> 3, klow = kk & 7;
        #pragma unroll
        for (int d = 0; d < 32; d++) {
            int dim = dh * 32 + d;
            Vt[dim * 128 + ((o + dim) & 15) * 8 + klow] = tmp[d];
        }
    }
    __syncthreads();

    int hi = lane >> 4;
    int lan15 = lane & 15;
    f32x4 sc[8];
    #pragma unroll
    for (int nt = 0; nt < 8; nt++) sc[nt] = (f32x4){0.f, 0.f, 0.f, 0.f};
    #pragma unroll
    for (int ks = 0; ks < 2; ks++) {
        int m = qr0 + lan15;
        int oA = ks * 4 + hi;
        bf16x8 a = *(const bf16x8*)&Qs[m * 64 + ((oA + m) & 7) * 8];
        #pragma unroll
        for (int nt = 0; nt < 8; nt++) {
            int n = nt * 16 + lan15;
            bf16x8 bb = *(const bf16x8*)&Ks[n * 64 + ((oA + n) & 7) * 8];
            sc[nt] = __builtin_amdgcn_mfma_f32_16x16x32_bf16(a, bb, sc[nt], 0, 0, 0);
        }
    }

    float lrow[4];
    #pragma unroll
    for (int r = 0; r < 4; r++) {
        int tq = t0 + qr0 + hi * 4 + r;
        float mx = -1e30f;
        #pragma unroll
        for (int nt = 0; nt < 8; nt++) {
            int s = k0 + nt * 16 + lan15;
            bool ok = (s >= 0) && (s <= tq) && (s >= tq - WIN);
            float vv = ok ? sc[nt][r] * 0.125f : -1e30f;
            sc[nt][r] = vv;
            mx = fmaxf(mx, vv);
        }
        #pragma unroll
        for (int off = 1; off < 16; off <<= 1) mx = fmaxf(mx, __shfl_xor(mx, off, 64));
        float ls = 0.f;
        #pragma unroll
        for (int nt = 0; nt < 8; nt++) {
            float e = __expf(sc[nt][r] - mx);
            sc[nt][r] = e;
            ls += e;
        }
        #pragma unroll
        for (int off = 1; off < 16; off <<= 1) ls += __shfl_xor(ls, off, 64);
        lrow[r] = ls;
    }

    #pragma unroll
    for (int nt = 0; nt < 8; nt++) {
        #pragma unroll
        for (int r = 0; r < 4; r++) {
            int row = qr0 + hi * 4 + r;
            int col = nt * 16 + lan15;
            Pl[row * 128 + (((col >> 3) + row) & 15) * 8 + (col & 7)] = f2bf(sc[nt][r]);
        }
    }
    __syncthreads();

    f32x4 y[4];
    #pragma unroll
    for (int nt = 0; nt < 4; nt++) y[nt] = (f32x4){0.f, 0.f, 0.f, 0.f};
    #pragma unroll
    for (int ks = 0; ks < 4; ks++) {
        int m = qr0 + lan15;
        int oA = ks * 4 + hi;
        bf16x8 a = *(const bf16x8*)&Pl[m * 128 + ((oA + m) & 15) * 8];
        #pragma unroll
        for (int nt = 0; nt < 4; nt++) {
            int n = nt * 16 + lan15;
            bf16x8 bb = *(const bf16x8*)&Vt[n * 128 + ((oA + n) & 15) * 8];
            y[nt] = __builtin_amdgcn_mfma_f32_16x16x32_bf16(a, bb, y[nt], 0, 0, 0);
        }
    }

    #pragma unroll
    for (int nt = 0; nt < 4; nt++) {
        #pragma unroll
        for (int r = 0; r < 4; r++) {
            int row = qr0 + hi * 4 + r;
            int dim = nt * 16 + lan15;
            cat_bf[(size_t)(b * TT + t0 + row) * (2 * DM) + DM + h * HD + dim] =
                f2bf(y[nt][r] / lrow[r]);
        }
    }
}

// ---------------------------------------------------------------------------
// Linear attention, phi-space chunked (CHUNK=64, PHI=153 padded to 160)
// ---------------------------------------------------------------------------
#define PHI 160
#define NCH 32
#define KVROWS 65
#define CH_STRIDE ((size_t)32 * KVROWS * PHI)

// Phase B: per-chunk KV^T via MFMA.  grid (32 chunks, 32 bh)
__global__ __launch_bounds__(256) void lin_kv_kernel(const unsigned short* __restrict__ kf,
                                                     const unsigned short* __restrict__ v_bf,
                                                     unsigned short* __restrict__ kvbuf) {
    int c = blockIdx.x, bh = blockIdx.y;
    int h = bh & 15, b = bh >> 4;
    int tid = threadIdx.x, lane = tid & 63, w = tid >> 6;
    int hi = lane >> 4, l15 = lane & 15;

    __shared__ unsigned short kf_l[64 * 16];
    __shared__ __align__(16) unsigned short PhiT[192 * 66];
    __shared__ __align__(16) unsigned short Vt[80 * 66];
    __shared__ int iu[136], ju[136];
    __shared__ float sclut[136];

    if (tid < 136) {
        int qq = tid, i = 0;
        while (qq >= 16 - i) { qq -= 16 - i; i++; }
        iu[tid] = i; ju[tid] = i + qq;
        sclut[tid] = (qq == 0) ? 0.5f : 0.70710678118654752f;
    }
    {
        int r = tid >> 2, f4 = (tid & 3) * 4;
        *(ushort4*)&kf_l[r * 16 + f4] =
            *(const ushort4*)&kf[((size_t)((b * TT + c * 64 + r) * NH + h)) * FEAT + f4];
    }
    {
        int p = tid & 31, dq = (tid >> 5) * 8;
        size_t base0 = ((size_t)(b * TT + c * 64 + 2 * p)) * DM + h * HD + dq;
        unsigned short a[8], bq[8];
        *(uint4*)a  = *(const uint4*)&v_bf[base0];
        *(uint4*)bq = *(const uint4*)&v_bf[base0 + DM];
        #pragma unroll
        for (int d = 0; d < 8; d++) {
            ushort2 u; u.x = a[d]; u.y = bq[d];
            *(ushort2*)&Vt[(dq + d) * 66 + 2 * p] = u;
        }
        #pragma unroll
        for (int i = 0; i < 4; i++) {
            int e = tid + i * 256;
            Vt[(64 + (e >> 6)) * 66 + (e & 63)] = 0x3F80;
        }
    }
    __syncthreads();
    {
        int s = tid & 63, fb = tid >> 6;
        float xr[16];
        #pragma unroll
        for (int i = 0; i < 16; i++) xr[i] = bf2f(kf_l[s * 16 + i]);
        for (int it = 0; it < 48; it++) {
            int f = fb + it * 4;
            float val;
            if (f == 0) val = 1.f;
            else if (f < 17) val = xr[f - 1];
            else if (f < 153) { int qq = f - 17; val = xr[iu[qq]] * xr[ju[qq]] * sclut[qq]; }
            else val = 0.f;
            PhiT[f * 66 + s] = f2bf(val);
        }
    }
    __syncthreads();
    f32x4 acc[5][3];
    #pragma unroll
    for (int m = 0; m < 5; m++)
        #pragma unroll
        for (int j = 0; j < 3; j++) acc[m][j] = (f32x4){0.f, 0.f, 0.f, 0.f};
    #pragma unroll
    for (int ks = 0; ks < 2; ks++) {
        bf16x8 bfrag[3];
        #pragma unroll
        for (int j = 0; j < 3; j++)
            bfrag[j] = *(const bf16x8*)&PhiT[((3 * w + j) * 16 + l15) * 66 + ks * 32 + hi * 8];
        #pragma unroll
        for (int m = 0; m < 5; m++) {
            bf16x8 afrag = *(const bf16x8*)&Vt[(m * 16 + l15) * 66 + ks * 32 + hi * 8];
            #pragma unroll
            for (int j = 0; j < 3; j++)
                acc[m][j] = __builtin_amdgcn_mfma_f32_16x16x32_bf16(afrag, bfrag[j], acc[m][j], 0, 0, 0);
        }
    }
    size_t obase = ((size_t)c * 32 + bh) * (KVROWS * PHI);
    #pragma unroll
    for (int m = 0; m < 5; m++) {
        #pragma unroll
        for (int j = 0; j < 3; j++) {
            int f = (3 * w + j) * 16 + l15;
            if (f >= PHI) continue;
            #pragma unroll
            for (int r = 0; r < 4; r++) {
                int row = m * 16 + hi * 4 + r;
                if (row >= KVROWS) continue;
                kvbuf[obase + row * PHI + f] = f2bf(acc[m][j][r]);
            }
        }
    }
}

// Phase C: in-place exclusive prefix over chunks. grid (41, 32 bh)
__global__ __launch_bounds__(256) void lin_scan_kernel(unsigned short* __restrict__ kvbuf) {
    int e = blockIdx.x * 256 + threadIdx.x;
    int bh = blockIdx.y;
    if (e >= KVROWS * PHI) return;
    float acc = 0.f;
    size_t off = (size_t)bh * (KVROWS * PHI) + e;
    for (int c = 0; c < NCH; c++) {
        float vv = bf2f(kvbuf[off]);
        kvbuf[off] = f2bf(acc);
        acc += vv;
        off += CH_STRIDE;
    }
}

// Phase D: outputs. grid (32 chunks, 32 bh).
__global__ __launch_bounds__(256) void lin_out_kernel(const unsigned short* __restrict__ qf,
                                                      const unsigned short* __restrict__ kf,
                                                      const unsigned short* __restrict__ v_bf,
                                                      const unsigned short* __restrict__ kvbuf,
                                                      unsigned short* __restrict__ cat_bf) {
    int c = blockIdx.x, bh = blockIdx.y;
    int h = bh & 15, b = bh >> 4;
    int tid = threadIdx.x, lane = tid & 63, w = tid >> 6;
    int hi = lane >> 4, l15 = lane & 15;

    __shared__ __align__(16) unsigned short kf_lb[64 * 34];
    __shared__ __align__(16) unsigned short KVS_l[80 * 162];
    __shared__ __align__(16) unsigned short Vt[80 * 66];
    __shared__ __align__(16) unsigned short P_l[64 * 66];
    __shared__ int iu[136], ju[136];
    __shared__ float sclut[136];

    if (tid < 136) {
        int qq = tid, i = 0;
        while (qq >= 16 - i) { qq -= 16 - i; i++; }
        iu[tid] = i; ju[tid] = i + qq;
        sclut[tid] = (qq == 0) ? 0.5f : 0.70710678118654752f;
    }
    {
        int r = tid >> 2, f4 = (tid & 3) * 4;
        *(ushort4*)&kf_lb[r * 34 + f4] =
            *(const ushort4*)&kf[((size_t)((b * TT + c * 64 + r) * NH + h)) * FEAT + f4];
        ushort4 z4 = {0, 0, 0, 0};
        *(ushort4*)&kf_lb[r * 34 + 16 + f4] = z4;
    }
    {
        int p = tid & 31, dq = (tid >> 5) * 8;
        size_t base0 = ((size_t)(b * TT + c * 64 + 2 * p)) * DM + h * HD + dq;
        unsigned short a[8], bq[8];
        *(uint4*)a  = *(const uint4*)&v_bf[base0];
        *(uint4*)bq = *(const uint4*)&v_bf[base0 + DM];
        #pragma unroll
        for (int d = 0; d < 8; d++) {
            ushort2 u; u.x = a[d]; u.y = bq[d];
            *(ushort2*)&Vt[(dq + d) * 66 + 2 * p] = u;
        }
        #pragma unroll
        for (int i = 0; i < 4; i++) {
            int e = tid + i * 256;
            Vt[(64 + (e >> 6)) * 66 + (e & 63)] = 0x3F80;
        }
    }
    {
        size_t gbase = ((size_t)c * 32 + bh) * (KVROWS * PHI);
        #pragma unroll
        for (int i = 0; i < 11; i++) {
            int e4 = tid + i * 256;
            if (e4 < KVROWS * 40) {
                int r = e4 / 40, f4 = (e4 % 40) * 4;
                *(ushort4*)&KVS_l[r * 162 + f4] =
                    *(const ushort4*)&kvbuf[gbase + r * PHI + f4];
            }
        }
        #pragma unroll
        for (int i = 0; i < 3; i++) {
            int e4 = tid + i * 256;
            if (e4 < 15 * 40) {
                int r = 65 + e4 / 40, f4 = (e4 % 40) * 4;
                ushort4 z4 = {0, 0, 0, 0};
                *(ushort4*)&KVS_l[r * 162 + f4] = z4;
            }
        }
    }
    int t_m = w * 16 + l15;
    float xr[16];
    {
        unsigned short qr[16];
        size_t qb = ((size_t)((b * TT + c * 64 + t_m) * NH + h)) * FEAT;
        *(ushort4*)&qr[0]  = *(const ushort4*)&qf[qb];
        *(ushort4*)&qr[4]  = *(const ushort4*)&qf[qb + 4];
        *(ushort4*)&qr[8]  = *(const ushort4*)&qf[qb + 8];
        *(ushort4*)&qr[12] = *(const ushort4*)&qf[qb + 12];
        #pragma unroll
        for (int i = 0; i < 16; i++) xr[i] = bf2f(qr[i]);
    }
    __syncthreads();

    f32x4 acc[5];
    #pragma unroll
    for (int n = 0; n < 5; n++) acc[n] = (f32x4){0.f, 0.f, 0.f, 0.f};

    #pragma unroll
    for (int ks = 0; ks < 5; ks++) {
        union { unsigned short u[8]; bf16x8 v; } af;
        int f0 = ks * 32 + hi * 8;
        #pragma unroll
        for (int j = 0; j < 8; j++) {
            int f = f0 + j;
            float val;
            if (f == 0) val = 1.f;
            else if (f < 17) val = xr[f - 1];
            else { int qq = f - 17; val = xr[iu[qq]] * xr[ju[qq]] * sclut[qq]; }
            af.u[j] = f2bf(val);
        }
        #pragma unroll
        for (int n = 0; n < 5; n++) {
            bf16x8 bb = *(const bf16x8*)&KVS_l[(n * 16 + l15) * 162 + ks * 32 + hi * 8];
            acc[n] = __builtin_amdgcn_mfma_f32_16x16x32_bf16(af.v, bb, acc[n], 0, 0, 0);
        }
    }

    {
        union { unsigned short u[8]; bf16x8 v; } aq;
        int f0 = hi * 8;
        #pragma unroll
        for (int j = 0; j < 8; j++) {
            int f = f0 + j;
            aq.u[j] = (f < 16) ? f2bf(xr[f]) : (unsigned short)0;
        }
        #pragma unroll
        for (int n = 0; n < 4; n++) {
            bf16x8 bk = *(const bf16x8*)&kf_lb[(n * 16 + l15) * 34 + hi * 8];
            f32x4 zv = {0.f, 0.f, 0.f, 0.f};
            f32x4 sc = __builtin_amdgcn_mfma_f32_16x16x32_bf16(aq.v, bk, zv, 0, 0, 0);
            int sl = n * 16 + l15;
            #pragma unroll
            for (int r = 0; r < 4; r++) {
                int rl = w * 16 + hi * 4 + r;
                float sv = 1.f + 0.5f * sc[r];
                sv = sv * sv;
                if (sl > rl) sv = 0.f;
                P_l[rl * 66 + sl] = f2bf(sv);
            }
        }
    }
    __syncthreads();

    #pragma unroll
    for (int ks = 0; ks < 2; ks++) {
        bf16x8 a = *(const bf16x8*)&P_l[(w * 16 + l15) * 66 + ks * 32 + hi * 8];
        #pragma unroll
        for (int n = 0; n < 5; n++) {
            bf16x8 bb = *(const bf16x8*)&Vt[(n * 16 + l15) * 66 + ks * 32 + hi * 8];
            acc[n] = __builtin_amdgcn_mfma_f32_16x16x32_bf16(a, bb, acc[n], 0, 0, 0);
        }
    }

    #pragma unroll
    for (int r = 0; r < 4; r++) {
        float zz = __shfl(acc[4][r], (lane & 48), 64);
        int token = c * 64 + w * 16 + hi * 4 + r;
        #pragma unroll
        for (int n = 0; n < 4; n++) {
            int d = n * 16 + l15;
            cat_bf[((size_t)(b * TT + token)) * (2 * DM) + h * HD + d] =
                f2bf(acc[n][r] / (zz + 1e-6f));
        }
    }
}

// ---------------------------------------------------------------------------
extern "C" void kernel_launch(void* const* d_in, const int* in_sizes, int n_in,
                              void* d_out, int out_size, void* d_ws, size_t ws_size,
                              hipStream_t stream) {
    const float* x      = (const float*)d_in[0];
    const float* norm_w = (const float*)d_in[1];
    const float* Wq     = (const float*)d_in[2];
    const float* Wk     = (const float*)d_in[3];
    const float* Wv     = (const float*)d_in[4];
    const float* Wqf    = (const float*)d_in[5];
    const float* Wkf    = (const float*)d_in[6];
    const float* Wout   = (const float*)d_in[7];
    float* out = (float*)d_out;

    char* p = (char*)d_ws;
    unsigned short* h_bf = (unsigned short*)p; p += (size_t)RTOT * DM * 2;       // 8 MB
    unsigned short* WqT  = (unsigned short*)p; p += (size_t)DM * DM * 2;         // 2 MB
    unsigned short* WkT  = (unsigned short*)p; p += (size_t)DM * DM * 2;
    unsigned short* WvT  = (unsigned short*)p; p += (size_t)DM * DM * 2;
    unsigned short* WoT  = (unsigned short*)p; p += (size_t)DM * 2 * DM * 2;     // 4 MB
    unsigned short* q_bf = (unsigned short*)p; p += (size_t)RTOT * DM * 2;       // 8 MB
    unsigned short* k_bf = (unsigned short*)p; p += (size_t)RTOT * DM * 2;
    unsigned short* v_bf = (unsigned short*)p; p += (size_t)RTOT * DM * 2;
    unsigned short* qf_bf = (unsigned short*)p; p += (size_t)RTOT * NH * FEAT * 2; // 2 MB
    unsigned short* kf_bf = (unsigned short*)p; p += (size_t)RTOT * NH * FEAT * 2;
    unsigned short* cat_bf = (unsigned short*)p; p += (size_t)RTOT * 2 * DM * 2;   // 16 MB
    unsigned short* kvbuf  = (unsigned short*)p; p += (size_t)NCH * 32 * KVROWS * PHI * 2; // 21.3 MB
    unsigned short* P0 = (unsigned short*)p; p += (size_t)RTOT * DM * 2;           // 8 MB
    unsigned short* P1 = (unsigned short*)p; p += (size_t)RTOT * DM * 2;           // 8 MB

    rmsnorm_kernel<<<RTOT, 256, 0, stream>>>(x, norm_w, h_bf);
    transpose_bf16_kernel<<<dim3(16, 32, 4), 256, 0, stream>>>(Wq, Wk, Wv, Wout, WqT, WkT, WvT, WoT);
    gemm_qkv_mfma<<<dim3(8, 32, 3), 256, 0, stream>>>(h_bf, WqT, WkT, WvT, q_bf, k_bf, v_bf);
    feat_kernel<<<dim3((RTOT * NH * FEAT) / 256, 1, 2), 256, 0, stream>>>(q_bf, k_bf, Wqf, Wkf, qf_bf, kf_bf);
    win_mfma_kernel<<<dim3(TT / 64, BB * NH), 256, 0, stream>>>(q_bf, k_bf, v_bf, cat_bf);
    lin_kv_kernel<<<dim3(NCH, BB * NH), 256, 0, stream>>>(kf_bf, v_bf, kvbuf);
    lin_scan_kernel<<<dim3((KVROWS * PHI + 255) / 256, BB * NH), 256, 0, stream>>>(kvbuf);
    lin_out_kernel<<<dim3(NCH, BB * NH), 256, 0, stream>>>(qf_bf, kf_bf, v_bf, kvbuf, cat_bf);
    gemm_out_mfma<<<dim3(8, 32, 2), 256, 0, stream>>>(cat_bf, WoT, P0, P1);
    out_reduce_kernel<<<RTOT * DM / 1024, 256, 0, stream>>>(x, P0, P1, out);
}

// Round 8
// 269.313 us; speedup vs baseline: 1.0747x; 1.0747x over previous
//
#include <hip/hip_runtime.h>
#include <math.h>

// Problem constants
#define BB 2
#define TT 2048
#define DM 1024
#define NH 16
#define HD 64
#define FEAT 16
#define WIN 64
#define RTOT (BB*TT)        // 4096 rows

typedef __bf16 bf16x8 __attribute__((ext_vector_type(8)));
typedef float  f32x4  __attribute__((ext_vector_type(4)));

__device__ __forceinline__ unsigned short f2bf(float f) {
    union { float f; unsigned u; } v; v.f = f;
    unsigned r = v.u + 0x7FFFu + ((v.u >> 16) & 1u);   // RNE
    return (unsigned short)(r >> 16);
}
__device__ __forceinline__ float bf2f(unsigned short u) {
    union { unsigned u; float f; } v; v.u = ((unsigned)u) << 16; return v.f;
}

__device__ __forceinline__ void gl2lds16(const void* g, void* l) {
    __builtin_amdgcn_global_load_lds(
        (const __attribute__((address_space(1))) void*)g,
        (__attribute__((address_space(3))) void*)l, 16, 0, 0);
}

// ---------------------------------------------------------------------------
// Kernel 1: RMSNorm -> bf16 output
// ---------------------------------------------------------------------------
__global__ __launch_bounds__(256) void rmsnorm_kernel(const float* __restrict__ x,
                                                      const float* __restrict__ w,
                                                      unsigned short* __restrict__ h_bf) {
    int row = blockIdx.x;
    int tid = threadIdx.x;
    const float4* xr = (const float4*)(x + (size_t)row * DM);
    float4 xv = xr[tid];
    float ss = xv.x*xv.x + xv.y*xv.y + xv.z*xv.z + xv.w*xv.w;
    #pragma unroll
    for (int off = 32; off > 0; off >>= 1) ss += __shfl_down(ss, off, 64);
    __shared__ float red[4];
    if ((tid & 63) == 0) red[tid >> 6] = ss;
    __syncthreads();
    float tot = red[0] + red[1] + red[2] + red[3];
    float scale = rsqrtf(tot * (1.0f / DM) + 1e-6f);
    float4 wv = ((const float4*)w)[tid];
    ushort4 o;
    o.x = f2bf(xv.x * scale * wv.x);
    o.y = f2bf(xv.y * scale * wv.y);
    o.z = f2bf(xv.z * scale * wv.z);
    o.w = f2bf(xv.w * scale * wv.w);
    *(ushort4*)&h_bf[(size_t)row * DM + tid * 4] = o;
}

// ---------------------------------------------------------------------------
// Kernel 2: transpose + fp32->bf16.  z=0..2: QKV (K=1024); z=3: Wout (K=2048).
// ---------------------------------------------------------------------------
__global__ __launch_bounds__(256) void transpose_bf16_kernel(const float* __restrict__ W0,
                                                             const float* __restrict__ W1,
                                                             const float* __restrict__ W2,
                                                             const float* __restrict__ W3,
                                                             unsigned short* __restrict__ T0,
                                                             unsigned short* __restrict__ T1,
                                                             unsigned short* __restrict__ T2,
                                                             unsigned short* __restrict__ T3) {
    int z = blockIdx.z;
    int K = (z == 3) ? 2048 : 1024;
    const int N = 1024;
    if (blockIdx.y * 64 >= K) return;
    const float* W = (z == 0) ? W0 : (z == 1) ? W1 : (z == 2) ? W2 : W3;
    unsigned short* WT = (z == 0) ? T0 : (z == 1) ? T1 : (z == 2) ? T2 : T3;
    __shared__ float tile[64][65];
    int k0 = blockIdx.y * 64, n0 = blockIdx.x * 64;
    int t = threadIdx.x;
    int r = t >> 4, c4 = (t & 15) * 4;
    #pragma unroll
    for (int i = 0; i < 4; i++) {
        float4 vv = *(const float4*)&W[(size_t)(k0 + r + i*16) * N + n0 + c4];
        tile[r + i*16][c4 + 0] = vv.x;
        tile[r + i*16][c4 + 1] = vv.y;
        tile[r + i*16][c4 + 2] = vv.z;
        tile[r + i*16][c4 + 3] = vv.w;
    }
    __syncthreads();
    int rn = t >> 2, kq = (t & 3) * 16;
    unsigned short u[16];
    #pragma unroll
    for (int i = 0; i < 16; i++) u[i] = f2bf(tile[kq + i][rn]);
    size_t base = (size_t)(n0 + rn) * K + k0 + kq;
    *(uint4*)&WT[base]     = *(uint4*)&u[0];
    *(uint4*)&WT[base + 8] = *(uint4*)&u[8];
}

// ---------------------------------------------------------------------------
// bf16 MFMA GEMM core, double-buffered, strength-reduced staging.
// ---------------------------------------------------------------------------
template<int LDA, int LDB>
__device__ __forceinline__ void gemm_core_db(const unsigned short* __restrict__ A,
                                             const unsigned short* __restrict__ BT,
                                             unsigned short* __restrict__ Cb,
                                             int k0g) {
    const int N = 1024;
    const int KITERS = 32;
    __shared__ __align__(16) unsigned short As[2 * 128 * 32];
    __shared__ __align__(16) unsigned short Bs[2 * 128 * 32];
    int tid = threadIdx.x;
    int lane = tid & 63;
    int w = tid >> 6;
    int wm = (w >> 1) * 64, wn = (w & 1) * 64;
    int m0 = blockIdx.y * 128, n0 = blockIdx.x * 128;
    int hi = lane >> 4;
    int l15 = lane & 15;

    int c0 = tid, c1 = tid + 256;
    int r0 = c0 >> 2, kh0 = ((c0 & 3) - (r0 >> 1)) & 3;
    int r1 = c1 >> 2, kh1 = ((c1 & 3) - (r1 >> 1)) & 3;
    const unsigned short* aP0 = A  + (size_t)(m0 + r0) * LDA + k0g + kh0 * 8;
    const unsigned short* aP1 = A  + (size_t)(m0 + r1) * LDA + k0g + kh1 * 8;
    const unsigned short* bP0 = BT + (size_t)(n0 + r0) * LDB + k0g + kh0 * 8;
    const unsigned short* bP1 = BT + (size_t)(n0 + r1) * LDB + k0g + kh1 * 8;
    unsigned short* asD0 = &As[c0 * 8];
    unsigned short* asD1 = &As[c1 * 8];
    unsigned short* bsD0 = &Bs[c0 * 8];
    unsigned short* bsD1 = &Bs[c1 * 8];

    int aOff[4], bOff[4];
    #pragma unroll
    for (int i = 0; i < 4; i++) {
        int m = wm + i * 16 + l15;
        aOff[i] = m * 32 + (((hi + (m >> 1)) & 3) * 8);
        int n = wn + i * 16 + l15;
        bOff[i] = n * 32 + (((hi + (n >> 1)) & 3) * 8);
    }

    f32x4 acc[4][4];
    #pragma unroll
    for (int i = 0; i < 4; i++)
        #pragma unroll
        for (int j = 0; j < 4; j++)
            acc[i][j] = (f32x4){0.f, 0.f, 0.f, 0.f};

    gl2lds16(aP0, asD0); gl2lds16(aP1, asD1);
    gl2lds16(bP0, bsD0); gl2lds16(bP1, bsD1);

    for (int it = 0; it < KITERS; it++) {
        int cur = (it & 1) * 4096;
        int nxt = 4096 - cur;
        __syncthreads();
        if (it + 1 < KITERS) {
            aP0 += 32; aP1 += 32; bP0 += 32; bP1 += 32;
            gl2lds16(aP0, asD0 + nxt); gl2lds16(aP1, asD1 + nxt);
            gl2lds16(bP0, bsD0 + nxt); gl2lds16(bP1, bsD1 + nxt);
        }
        bf16x8 af[4], bfr[4];
        #pragma unroll
        for (int i = 0; i < 4; i++) {
            af[i]  = *(const bf16x8*)&As[cur + aOff[i]];
            bfr[i] = *(const bf16x8*)&Bs[cur + bOff[i]];
        }
        #pragma unroll
        for (int i = 0; i < 4; i++)
            #pragma unroll
            for (int j = 0; j < 4; j++)
                acc[i][j] = __builtin_amdgcn_mfma_f32_16x16x32_bf16(af[i], bfr[j], acc[i][j], 0, 0, 0);
    }
    #pragma unroll
    for (int i = 0; i < 4; i++) {
        #pragma unroll
        for (int j = 0; j < 4; j++) {
            int col = n0 + wn + j * 16 + l15;
            #pragma unroll
            for (int r = 0; r < 4; r++) {
                int row = m0 + wm + i * 16 + hi * 4 + r;
                Cb[(size_t)row * N + col] = f2bf(acc[i][j][r]);
            }
        }
    }
}

__global__ __launch_bounds__(256) void gemm_qkv_mfma(const unsigned short* __restrict__ A,
                                                     const unsigned short* __restrict__ BT0,
                                                     const unsigned short* __restrict__ BT1,
                                                     const unsigned short* __restrict__ BT2,
                                                     unsigned short* __restrict__ C0,
                                                     unsigned short* __restrict__ C1,
                                                     unsigned short* __restrict__ C2) {
    const unsigned short* BT = (blockIdx.z == 0) ? BT0 : (blockIdx.z == 1) ? BT1 : BT2;
    unsigned short* C = (blockIdx.z == 0) ? C0 : (blockIdx.z == 1) ? C1 : C2;
    gemm_core_db<1024, 1024>(A, BT, C, 0);
}

__global__ __launch_bounds__(256) void gemm_out_mfma(const unsigned short* __restrict__ A,
                                                     const unsigned short* __restrict__ BT,
                                                     unsigned short* __restrict__ P0,
                                                     unsigned short* __restrict__ P1) {
    unsigned short* P = (blockIdx.z == 0) ? P0 : P1;
    gemm_core_db<2048, 2048>(A, BT, P, blockIdx.z * 1024);
}

__global__ __launch_bounds__(256) void out_reduce_kernel(const float* __restrict__ x,
                                                         const unsigned short* __restrict__ P0,
                                                         const unsigned short* __restrict__ P1,
                                                         float* __restrict__ out) {
    int g = blockIdx.x * 256 + threadIdx.x;
    size_t e = (size_t)g * 4;
    float4 xv = *(const float4*)&x[e];
    ushort4 a = *(const ushort4*)&P0[e];
    ushort4 b = *(const ushort4*)&P1[e];
    float4 o;
    o.x = xv.x + bf2f(a.x) + bf2f(b.x);
    o.y = xv.y + bf2f(a.y) + bf2f(b.y);
    o.z = xv.z + bf2f(a.z) + bf2f(b.z);
    o.w = xv.w + bf2f(a.w) + bf2f(b.w);
    *(float4*)&out[e] = o;
}

// ---------------------------------------------------------------------------
// Kernel 3: feature projection (bf16 in, bf16 out)
// ---------------------------------------------------------------------------
__global__ __launch_bounds__(256) void feat_kernel(const unsigned short* __restrict__ qb,
                                                   const unsigned short* __restrict__ kb,
                                                   const float* __restrict__ Wqf,
                                                   const float* __restrict__ Wkf,
                                                   unsigned short* __restrict__ qf,
                                                   unsigned short* __restrict__ kf) {
    __shared__ float Wl[HD * FEAT];
    const unsigned short* src = blockIdx.z ? kb : qb;
    const float* Wm = blockIdx.z ? Wkf : Wqf;
    unsigned short* dst = blockIdx.z ? kf : qf;
    int tid = threadIdx.x;
    ((float4*)Wl)[tid] = ((const float4*)Wm)[tid];
    __syncthreads();
    int gid = blockIdx.x * 256 + tid;
    int f = gid & 15;
    int rowh = gid >> 4;
    const unsigned short* s = src + (size_t)rowh * HD;
    float acc = 0.f;
    #pragma unroll
    for (int d = 0; d < HD; d++) acc += bf2f(s[d]) * Wl[d * FEAT + f];
    dst[gid] = f2bf(acc);
}

// ---------------------------------------------------------------------------
// Kernel 4: sliding-window attention, single-shot MFMA flash tile.
// ---------------------------------------------------------------------------
__global__ __launch_bounds__(256) void win_mfma_kernel(const unsigned short* __restrict__ q_bf,
                                                       const unsigned short* __restrict__ k_bf,
                                                       const unsigned short* __restrict__ v_bf,
                                                       unsigned short* __restrict__ cat_bf) {
    int qtile = blockIdx.x;
    int bh = blockIdx.y;
    int h = bh & 15;
    int b = bh >> 4;
    int tid = threadIdx.x;
    int lane = tid & 63;
    int wv = tid >> 6;
    int qr0 = wv * 16;
    int t0 = qtile * 64;
    int k0 = t0 - 64;

    __shared__ __align__(16) unsigned short Qs[64 * 64];
    __shared__ __align__(16) unsigned short Ks[128 * 64];
    __shared__ __align__(16) unsigned short Vt[64 * 128];
    __shared__ __align__(16) unsigned short Pl[64 * 128];

    #pragma unroll
    for (int half = 0; half < 2; half++) {
        int slot = tid + half * 256;
        int row = slot >> 3, pos = slot & 7;
        int o = (pos - row) & 7;
        gl2lds16(q_bf + (size_t)(b * TT + t0 + row) * (NH * HD) + h * HD + o * 8,
                 &Qs[slot * 8]);
    }
    #pragma unroll
    for (int qd = 0; qd < 4; qd++) {
        int slot = tid + qd * 256;
        int row = slot >> 3, pos = slot & 7;
        int o = (pos - row) & 7;
        int kg = k0 + row;
        if (kg >= 0) {
            gl2lds16(k_bf + (size_t)(b * TT + kg) * (NH * HD) + h * HD + o * 8,
                     &Ks[slot * 8]);
        } else {
            uint4 z = {0, 0, 0, 0};
            *(uint4*)&Ks[slot * 8] = z;
        }
    }
    {
        int kk = tid & 127;
        int dh = tid >> 7;
        int kg = k0 + kk;
        unsigned short tmp[32];
        if (kg >= 0) {
            size_t base = (size_t)(b * TT + kg) * (NH * HD) + h * HD + dh * 32;
            *(uint4*)&tmp[0]  = *(const uint4*)&v_bf[base];
            *(uint4*)&tmp[8]  = *(const uint4*)&v_bf[base + 8];
            *(uint4*)&tmp[16] = *(const uint4*)&v_bf[base + 16];
            *(uint4*)&tmp[24] = *(const uint4*)&v_bf[base + 24];
        } else {
            #pragma unroll
            for (int d = 0; d < 32; d++) tmp[d] = 0;
        }
        int o = kk >> 3, klow = kk & 7;
        #pragma unroll
        for (int d = 0; d < 32; d++) {
            int dim = dh * 32 + d;
            Vt[dim * 128 + ((o + dim) & 15) * 8 + klow] = tmp[d];
        }
    }
    __syncthreads();

    int hi = lane >> 4;
    int lan15 = lane & 15;
    f32x4 sc[8];
    #pragma unroll
    for (int nt = 0; nt < 8; nt++) sc[nt] = (f32x4){0.f, 0.f, 0.f, 0.f};
    #pragma unroll
    for (int ks = 0; ks < 2; ks++) {
        int m = qr0 + lan15;
        int oA = ks * 4 + hi;
        bf16x8 a = *(const bf16x8*)&Qs[m * 64 + ((oA + m) & 7) * 8];
        #pragma unroll
        for (int nt = 0; nt < 8; nt++) {
            int n = nt * 16 + lan15;
            bf16x8 bb = *(const bf16x8*)&Ks[n * 64 + ((oA + n) & 7) * 8];
            sc[nt] = __builtin_amdgcn_mfma_f32_16x16x32_bf16(a, bb, sc[nt], 0, 0, 0);
        }
    }

    float lrow[4];
    #pragma unroll
    for (int r = 0; r < 4; r++) {
        int tq = t0 + qr0 + hi * 4 + r;
        float mx = -1e30f;
        #pragma unroll
        for (int nt = 0; nt < 8; nt++) {
            int s = k0 + nt * 16 + lan15;
            bool ok = (s >= 0) && (s <= tq) && (s >= tq - WIN);
            float vv = ok ? sc[nt][r] * 0.125f : -1e30f;
            sc[nt][r] = vv;
            mx = fmaxf(mx, vv);
        }
        #pragma unroll
        for (int off = 1; off < 16; off <<= 1) mx = fmaxf(mx, __shfl_xor(mx, off, 64));
        float ls = 0.f;
        #pragma unroll
        for (int nt = 0; nt < 8; nt++) {
            float e = __expf(sc[nt][r] - mx);
            sc[nt][r] = e;
            ls += e;
        }
        #pragma unroll
        for (int off = 1; off < 16; off <<= 1) ls += __shfl_xor(ls, off, 64);
        lrow[r] = ls;
    }

    #pragma unroll
    for (int nt = 0; nt < 8; nt++) {
        #pragma unroll
        for (int r = 0; r < 4; r++) {
            int row = qr0 + hi * 4 + r;
            int col = nt * 16 + lan15;
            Pl[row * 128 + (((col >> 3) + row) & 15) * 8 + (col & 7)] = f2bf(sc[nt][r]);
        }
    }
    __syncthreads();

    f32x4 y[4];
    #pragma unroll
    for (int nt = 0; nt < 4; nt++) y[nt] = (f32x4){0.f, 0.f, 0.f, 0.f};
    #pragma unroll
    for (int ks = 0; ks < 4; ks++) {
        int m = qr0 + lan15;
        int oA = ks * 4 + hi;
        bf16x8 a = *(const bf16x8*)&Pl[m * 128 + ((oA + m) & 15) * 8];
        #pragma unroll
        for (int nt = 0; nt < 4; nt++) {
            int n = nt * 16 + lan15;
            bf16x8 bb = *(const bf16x8*)&Vt[n * 128 + ((oA + n) & 15) * 8];
            y[nt] = __builtin_amdgcn_mfma_f32_16x16x32_bf16(a, bb, y[nt], 0, 0, 0);
        }
    }

    #pragma unroll
    for (int nt = 0; nt < 4; nt++) {
        #pragma unroll
        for (int r = 0; r < 4; r++) {
            int row = qr0 + hi * 4 + r;
            int dim = nt * 16 + lan15;
            cat_bf[(size_t)(b * TT + t0 + row) * (2 * DM) + DM + h * HD + dim] =
                f2bf(y[nt][r] / lrow[r]);
        }
    }
}

// ---------------------------------------------------------------------------
// Linear attention, phi-space chunked (CHUNK=64, PHI=153 padded to 160)
// phi index LUTs are size 136 (quadratic terms f=17..152). f in [153,160)
// is ZERO padding — the f<153 guard below is correctness-critical (R7 bug:
// missing guard read iu/ju OOB -> garbage in kvbuf cols 153..159 -> NaN).
// ---------------------------------------------------------------------------
#define PHI 160
#define NCH 32
#define KVROWS 65
#define CH_STRIDE ((size_t)32 * KVROWS * PHI)

// Phase B: per-chunk KV^T via MFMA.  grid (32 chunks, 32 bh)
__global__ __launch_bounds__(256) void lin_kv_kernel(const unsigned short* __restrict__ kf,
                                                     const unsigned short* __restrict__ v_bf,
                                                     unsigned short* __restrict__ kvbuf) {
    int c = blockIdx.x, bh = blockIdx.y;
    int h = bh & 15, b = bh >> 4;
    int tid = threadIdx.x, lane = tid & 63, w = tid >> 6;
    int hi = lane >> 4, l15 = lane & 15;

    __shared__ unsigned short kf_l[64 * 16];
    __shared__ __align__(16) unsigned short PhiT[192 * 76];  // [f][token]; rows>=160 garbage (discarded)
    __shared__ __align__(16) unsigned short Vt[80 * 64];     // swizzled [d|ones][token]
    __shared__ unsigned short iu[136], ju[136];
    __shared__ float sclut[136];

    if (tid < 136) {
        int qq = tid, i = 0;
        while (qq >= 16 - i) { qq -= 16 - i; i++; }
        iu[tid] = (unsigned short)i; ju[tid] = (unsigned short)(i + qq);
        sclut[tid] = (qq == 0) ? 0.5f : 0.70710678118654752f;
    }
    {   // stage kf (64x16)
        int r = tid >> 2, f4 = (tid & 3) * 4;
        *(ushort4*)&kf_l[r * 16 + f4] =
            *(const ushort4*)&kf[((size_t)((b * TT + c * 64 + r) * NH + h)) * FEAT + f4];
    }
    {   // stage V^T swizzled + ones rows 64..79
        int p = tid & 31, dq = (tid >> 5) * 8;
        size_t base0 = ((size_t)(b * TT + c * 64 + 2 * p)) * DM + h * HD + dq;
        unsigned short a[8], bq[8];
        *(uint4*)a  = *(const uint4*)&v_bf[base0];
        *(uint4*)bq = *(const uint4*)&v_bf[base0 + DM];
        int colo = p >> 2, coll = (2 * p) & 7;
        #pragma unroll
        for (int d = 0; d < 8; d++) {
            int row = dq + d;
            ushort2 u; u.x = a[d]; u.y = bq[d];
            *(ushort2*)&Vt[row * 64 + ((colo + row) & 7) * 8 + coll] = u;
        }
        #pragma unroll
        for (int i = 0; i < 4; i++) {
            int e = tid + i * 256;
            Vt[(64 + (e >> 6)) * 64 + (e & 63)] = 0x3F80;
        }
    }
    __syncthreads();
    {   // build PhiT[f][token], f wave-uniform, features read from LDS
        int s = tid & 63, fb = tid >> 6;
        const unsigned short* krow = &kf_l[s * 16];
        for (int it = 0; it < 40; it++) {
            int f = fb * 40 + it;
            float val;
            if (f == 0) val = 1.f;
            else if (f < 17) val = bf2f(krow[f - 1]);
            else if (f < 153) { int qq = f - 17; val = bf2f(krow[iu[qq]]) * bf2f(krow[ju[qq]]) * sclut[qq]; }
            else val = 0.f;   // f in [153,160): zero padding (guard is load-bearing!)
            PhiT[f * 76 + s] = f2bf(val);
        }
    }
    __syncthreads();
    f32x4 acc[5][3];
    #pragma unroll
    for (int m = 0; m < 5; m++)
        #pragma unroll
        for (int j = 0; j < 3; j++) acc[m][j] = (f32x4){0.f, 0.f, 0.f, 0.f};
    #pragma unroll
    for (int ks = 0; ks < 2; ks++) {
        bf16x8 bfrag[3];
        #pragma unroll
        for (int j = 0; j < 3; j++)
            bfrag[j] = *(const bf16x8*)&PhiT[((3 * w + j) * 16 + l15) * 76 + ks * 32 + hi * 8];
        #pragma unroll
        for (int m = 0; m < 5; m++) {
            int mrow = m * 16 + l15;
            bf16x8 afrag = *(const bf16x8*)&Vt[mrow * 64 + (((ks * 4 + hi) + mrow) & 7) * 8];
            #pragma unroll
            for (int j = 0; j < 3; j++)
                acc[m][j] = __builtin_amdgcn_mfma_f32_16x16x32_bf16(afrag, bfrag[j], acc[m][j], 0, 0, 0);
        }
    }
    size_t obase = ((size_t)c * 32 + bh) * (KVROWS * PHI);
    #pragma unroll
    for (int m = 0; m < 5; m++) {
        #pragma unroll
        for (int j = 0; j < 3; j++) {
            int f = (3 * w + j) * 16 + l15;
            if (f >= PHI) continue;
            #pragma unroll
            for (int r = 0; r < 4; r++) {
                int row = m * 16 + hi * 4 + r;
                if (row >= KVROWS) continue;
                kvbuf[obase + row * PHI + f] = f2bf(acc[m][j][r]);
            }
        }
    }
}

// Phase C: in-place exclusive prefix over chunks. grid (41, 32 bh)
__global__ __launch_bounds__(256) void lin_scan_kernel(unsigned short* __restrict__ kvbuf) {
    int e = blockIdx.x * 256 + threadIdx.x;
    int bh = blockIdx.y;
    if (e >= KVROWS * PHI) return;
    float acc = 0.f;
    size_t off = (size_t)bh * (KVROWS * PHI) + e;
    for (int c = 0; c < NCH; c++) {
        float vv = bf2f(kvbuf[off]);
        kvbuf[off] = f2bf(acc);
        acc += vv;
        off += CH_STRIDE;
    }
}

// Phase D: outputs. grid (32 chunks, 32 bh). Wave w owns token rows w*16..+15.
__global__ __launch_bounds__(256) void lin_out_kernel(const unsigned short* __restrict__ qf,
                                                      const unsigned short* __restrict__ kf,
                                                      const unsigned short* __restrict__ v_bf,
                                                      const unsigned short* __restrict__ kvbuf,
                                                      unsigned short* __restrict__ cat_bf) {
    int c = blockIdx.x, bh = blockIdx.y;
    int h = bh & 15, b = bh >> 4;
    int tid = threadIdx.x, lane = tid & 63, w = tid >> 6;
    int hi = lane >> 4, l15 = lane & 15;

    __shared__ unsigned short qf_l[64 * 16];
    __shared__ __align__(16) unsigned short kf_lb[64 * 34];   // cols 16..31 zero
    __shared__ __align__(16) unsigned short KVS_l[80 * 164];  // rows 65..79 zero
    __shared__ __align__(16) unsigned short Vt[80 * 64];      // swizzled + ones rows
    __shared__ __align__(16) unsigned short Phi_l[64 * 164];  // [token][f]
    __shared__ __align__(16) unsigned short P_l[64 * 64];     // swizzled
    __shared__ unsigned short iu[136], ju[136];
    __shared__ float sclut[136];

    if (tid < 136) {
        int qq = tid, i = 0;
        while (qq >= 16 - i) { qq -= 16 - i; i++; }
        iu[tid] = (unsigned short)i; ju[tid] = (unsigned short)(i + qq);
        sclut[tid] = (qq == 0) ? 0.5f : 0.70710678118654752f;
    }
    {   // stage qf (64x16)
        int r = tid >> 2, f4 = (tid & 3) * 4;
        *(ushort4*)&qf_l[r * 16 + f4] =
            *(const ushort4*)&qf[((size_t)((b * TT + c * 64 + r) * NH + h)) * FEAT + f4];
    }
    {   // stage kf with zero pad
        int r = tid >> 2, f4 = (tid & 3) * 4;
        *(ushort4*)&kf_lb[r * 34 + f4] =
            *(const ushort4*)&kf[((size_t)((b * TT + c * 64 + r) * NH + h)) * FEAT + f4];
        ushort4 z4 = {0, 0, 0, 0};
        *(ushort4*)&kf_lb[r * 34 + 16 + f4] = z4;
    }
    {   // stage V^T swizzled + ones rows
        int p = tid & 31, dq = (tid >> 5) * 8;
        size_t base0 = ((size_t)(b * TT + c * 64 + 2 * p)) * DM + h * HD + dq;
        unsigned short a[8], bq[8];
        *(uint4*)a  = *(const uint4*)&v_bf[base0];
        *(uint4*)bq = *(const uint4*)&v_bf[base0 + DM];
        int colo = p >> 2, coll = (2 * p) & 7;
        #pragma unroll
        for (int d = 0; d < 8; d++) {
            int row = dq + d;
            ushort2 u; u.x = a[d]; u.y = bq[d];
            *(ushort2*)&Vt[row * 64 + ((colo + row) & 7) * 8 + coll] = u;
        }
        #pragma unroll
        for (int i = 0; i < 4; i++) {
            int e = tid + i * 256;
            Vt[(64 + (e >> 6)) * 64 + (e & 63)] = 0x3F80;
        }
    }
    {   // stage KVS rows 0..64 (stride 164), zero rows 65..79
        size_t gbase = ((size_t)c * 32 + bh) * (KVROWS * PHI);
        #pragma unroll
        for (int i = 0; i < 11; i++) {
            int e4 = tid + i * 256;
            if (e4 < KVROWS * 40) {
                int r = e4 / 40, q4 = (e4 % 40) * 4;
                *(ushort4*)&KVS_l[r * 164 + q4] =
                    *(const ushort4*)&kvbuf[gbase + r * PHI + q4];
            }
        }
        #pragma unroll
        for (int i = 0; i < 3; i++) {
            int e4 = tid + i * 256;
            if (e4 < 15 * 40) {
                int r = 65 + e4 / 40, q4 = (e4 % 40) * 4;
                ushort4 z4 = {0, 0, 0, 0};
                *(ushort4*)&KVS_l[r * 164 + q4] = z4;
            }
        }
    }
    __syncthreads();

    {   // build Phi_l[token][f], f wave-uniform, features via LDS reads
        int s = tid & 63, fb = tid >> 6;
        const unsigned short* qrow = &qf_l[s * 16];
        for (int it = 0; it < 40; it++) {
            int f = fb * 40 + it;
            float val;
            if (f == 0) val = 1.f;
            else if (f < 17) val = bf2f(qrow[f - 1]);
            else if (f < 153) { int qq = f - 17; val = bf2f(qrow[iu[qq]]) * bf2f(qrow[ju[qq]]) * sclut[qq]; }
            else val = 0.f;   // f in [153,160): zero padding (guard is load-bearing!)
            Phi_l[s * 164 + f] = f2bf(val);
        }
    }
    __syncthreads();

    f32x4 acc[5];
    #pragma unroll
    for (int n = 0; n < 5; n++) acc[n] = (f32x4){0.f, 0.f, 0.f, 0.f};

    int t_m = w * 16 + l15;

    // GEMM1: Phi (LDS) x KVS
    #pragma unroll
    for (int ks = 0; ks < 5; ks++) {
        bf16x8 af = *(const bf16x8*)&Phi_l[t_m * 164 + ks * 32 + hi * 8];
        #pragma unroll
        for (int n = 0; n < 5; n++) {
            bf16x8 bb = *(const bf16x8*)&KVS_l[(n * 16 + l15) * 164 + ks * 32 + hi * 8];
            acc[n] = __builtin_amdgcn_mfma_f32_16x16x32_bf16(af, bb, acc[n], 0, 0, 0);
        }
    }

    // intra-chunk scores: S = (1 + qf.kf/2)^2, causal (diag included)
    {
        union { unsigned short u[8]; bf16x8 v; } aq;
        #pragma unroll
        for (int j = 0; j < 8; j++) {
            int f = hi * 8 + j;
            aq.u[j] = (f < 16) ? qf_l[t_m * 16 + f] : (unsigned short)0;
        }
        #pragma unroll
        for (int n = 0; n < 4; n++) {
            bf16x8 bk = *(const bf16x8*)&kf_lb[(n * 16 + l15) * 34 + hi * 8];
            f32x4 zv = {0.f, 0.f, 0.f, 0.f};
            f32x4 sc = __builtin_amdgcn_mfma_f32_16x16x32_bf16(aq.v, bk, zv, 0, 0, 0);
            int sl = n * 16 + l15;
            #pragma unroll
            for (int r = 0; r < 4; r++) {
                int rl = w * 16 + hi * 4 + r;
                float sv = 1.f + 0.5f * sc[r];
                sv = sv * sv;
                if (sl > rl) sv = 0.f;
                P_l[rl * 64 + (((sl >> 3) + rl) & 7) * 8 + (sl & 7)] = f2bf(sv);
            }
        }
    }
    __syncthreads();

    // GEMM2: P x Vt (y into cols 0..63, z into col 64 via ones rows)
    #pragma unroll
    for (int ks = 0; ks < 2; ks++) {
        int oA = ks * 4 + hi;
        bf16x8 a = *(const bf16x8*)&P_l[t_m * 64 + ((oA + t_m) & 7) * 8];
        #pragma unroll
        for (int n = 0; n < 5; n++) {
            int nrow = n * 16 + l15;
            bf16x8 bb = *(const bf16x8*)&Vt[nrow * 64 + ((oA + nrow) & 7) * 8];
            acc[n] = __builtin_amdgcn_mfma_f32_16x16x32_bf16(a, bb, acc[n], 0, 0, 0);
        }
    }

    // epilogue: z lives in col 64 (l15==0 of acc[4]); broadcast per row
    #pragma unroll
    for (int r = 0; r < 4; r++) {
        float zz = __shfl(acc[4][r], (lane & 48), 64);
        int token = c * 64 + w * 16 + hi * 4 + r;
        #pragma unroll
        for (int n = 0; n < 4; n++) {
            int d = n * 16 + l15;
            cat_bf[((size_t)(b * TT + token)) * (2 * DM) + h * HD + d] =
                f2bf(acc[n][r] / (zz + 1e-6f));
        }
    }
}

// ---------------------------------------------------------------------------
extern "C" void kernel_launch(void* const* d_in, const int* in_sizes, int n_in,
                              void* d_out, int out_size, void* d_ws, size_t ws_size,
                              hipStream_t stream) {
    const float* x      = (const float*)d_in[0];
    const float* norm_w = (const float*)d_in[1];
    const float* Wq     = (const float*)d_in[2];
    const float* Wk     = (const float*)d_in[3];
    const float* Wv     = (const float*)d_in[4];
    const float* Wqf    = (const float*)d_in[5];
    const float* Wkf    = (const float*)d_in[6];
    const float* Wout   = (const float*)d_in[7];
    float* out = (float*)d_out;

    char* p = (char*)d_ws;
    unsigned short* h_bf = (unsigned short*)p; p += (size_t)RTOT * DM * 2;       // 8 MB
    unsigned short* WqT  = (unsigned short*)p; p += (size_t)DM * DM * 2;         // 2 MB
    unsigned short* WkT  = (unsigned short*)p; p += (size_t)DM * DM * 2;
    unsigned short* WvT  = (unsigned short*)p; p += (size_t)DM * DM * 2;
    unsigned short* WoT  = (unsigned short*)p; p += (size_t)DM * 2 * DM * 2;     // 4 MB
    unsigned short* q_bf = (unsigned short*)p; p += (size_t)RTOT * DM * 2;       // 8 MB
    unsigned short* k_bf = (unsigned short*)p; p += (size_t)RTOT * DM * 2;
    unsigned short* v_bf = (unsigned short*)p; p += (size_t)RTOT * DM * 2;
    unsigned short* qf_bf = (unsigned short*)p; p += (size_t)RTOT * NH * FEAT * 2; // 2 MB
    unsigned short* kf_bf = (unsigned short*)p; p += (size_t)RTOT * NH * FEAT * 2;
    unsigned short* cat_bf = (unsigned short*)p; p += (size_t)RTOT * 2 * DM * 2;   // 16 MB
    unsigned short* kvbuf  = (unsigned short*)p; p += (size_t)NCH * 32 * KVROWS * PHI * 2; // 21.3 MB
    unsigned short* P0 = (unsigned short*)p; p += (size_t)RTOT * DM * 2;           // 8 MB
    unsigned short* P1 = (unsigned short*)p; p += (size_t)RTOT * DM * 2;           // 8 MB

    rmsnorm_kernel<<<RTOT, 256, 0, stream>>>(x, norm_w, h_bf);
    transpose_bf16_kernel<<<dim3(16, 32, 4), 256, 0, stream>>>(Wq, Wk, Wv, Wout, WqT, WkT, WvT, WoT);
    gemm_qkv_mfma<<<dim3(8, 32, 3), 256, 0, stream>>>(h_bf, WqT, WkT, WvT, q_bf, k_bf, v_bf);
    feat_kernel<<<dim3((RTOT * NH * FEAT) / 256, 1, 2), 256, 0, stream>>>(q_bf, k_bf, Wqf, Wkf, qf_bf, kf_bf);
    win_mfma_kernel<<<dim3(TT / 64, BB * NH), 256, 0, stream>>>(q_bf, k_bf, v_bf, cat_bf);
    lin_kv_kernel<<<dim3(NCH, BB * NH), 256, 0, stream>>>(kf_bf, v_bf, kvbuf);
    lin_scan_kernel<<<dim3((KVROWS * PHI + 255) / 256, BB * NH), 256, 0, stream>>>(kvbuf);
    lin_out_kernel<<<dim3(NCH, BB * NH), 256, 0, stream>>>(qf_bf, kf_bf, v_bf, kvbuf, cat_bf);
    gemm_out_mfma<<<dim3(8, 32, 2), 256, 0, stream>>>(cat_bf, WoT, P0, P1);
    out_reduce_kernel<<<RTOT * DM / 1024, 256, 0, stream>>>(x, P0, P1, out);
}